// Round 17
// baseline (169.992 us; speedup 1.0000x reference)
//
#include <hip/hip_runtime.h>

// Match numpy f32 semantics: no FMA contraction anywhere in this TU.
#pragma clang fp contract(off)

#define VWD 96
#define NVERT 2048
#define NFAC 512
#define NBATCH 8
#define NSLAB 1728          // 12 x 12 x 12 slabs of 8x8x8 voxels
#define RECF 16             // floats per facet body record
#define CULC 94             // cull comps (SoA): bbox 6 + 4 planes x 4 + 18 SAT axes x 4

// SoA cull addressing: component c, batch b, facet f
#define CUL(c, b, f) cul[(size_t)(c) * (NBATCH * NFAC) + (size_t)(b) * NFAC + (f)]

// ---------------------------------------------------------------------------
// Kernel 1: per-batch facet precompute, |det|-descending one-barrier rank
// sort, sign-folded body records, full 25-axis SAT cull data (conservative,
// margin-inflated, 8x8x8-slab half-extents folded: HX=HY=HZ=7/96).
// ---------------------------------------------------------------------------
__global__ __launch_bounds__(512) void precompute_kernel(
    const float* __restrict__ vertices,
    const int*   __restrict__ facets,
    float*       __restrict__ cul,
    float*       __restrict__ body)
{
    __shared__ unsigned skey[NFAC];
    const int b = blockIdx.x;
    const int j = threadIdx.x;          // one facet per thread
    const float* vb = vertices + (size_t)b * NVERT * 3;

    int4 fi = ((const int4*)facets)[b * NFAC + j];
    float x0 = vb[3*fi.x+0], y0 = vb[3*fi.x+1], z0 = vb[3*fi.x+2];
    float x1 = vb[3*fi.y+0], y1 = vb[3*fi.y+1], z1 = vb[3*fi.y+2];
    float x2 = vb[3*fi.z+0], y2 = vb[3*fi.z+1], z2 = vb[3*fi.z+2];
    float x3 = vb[3*fi.w+0], y3 = vb[3*fi.w+1], z3 = vb[3*fi.w+2];
    float a  = x0-x3, bb = x1-x3, c  = x2-x3;
    float d  = y0-y3, e  = y1-y3, f  = y2-y3;
    float g  = z0-z3, h  = z1-z3, ii = z2-z3;
    float A00 = e*ii - f*h,  A01 = c*h  - bb*ii, A02 = bb*f - c*e;
    float A10 = f*g  - d*ii, A11 = a*ii - c*g,   A12 = c*d  - a*f;
    float A20 = d*h  - e*g,  A21 = bb*g - a*h,   A22 = a*e  - bb*d;
    float det = a*(e*ii - f*h) - bb*(d*ii - f*g) + c*(d*h - e*g);
    if (det < 0.0f) {   // sign-fold (exact)
        det = -det;
        A00 = -A00; A01 = -A01; A02 = -A02;
        A10 = -A10; A11 = -A11; A12 = -A12;
        A20 = -A20; A21 = -A21; A22 = -A22;
    }
    unsigned myk = ~__float_as_uint(det);   // ascending key == descending |det|
    skey[j] = myk;
    __syncthreads();

    // rank = #{k : key_k < myk or (key_k == myk and k < j)}  -> unique slot
    int rank = 0;
    const uint4* sk4 = (const uint4*)skey;
    for (int k0 = 0; k0 < NFAC; k0 += 4) {
        uint4 kk = sk4[k0 >> 2];
        rank += (kk.x < myk) + ((kk.x == myk) & (k0 + 0 < j));
        rank += (kk.y < myk) + ((kk.y == myk) & (k0 + 1 < j));
        rank += (kk.z < myk) + ((kk.z == myk) & (k0 + 2 < j));
        rank += (kk.w < myk) + ((kk.w == myk) & (k0 + 3 < j));
    }

    CUL(0, b, rank) = fminf(fminf(x0,x1),fminf(x2,x3)) - 1e-4f;
    CUL(1, b, rank) = fminf(fminf(y0,y1),fminf(y2,y3)) - 1e-4f;
    CUL(2, b, rank) = fminf(fminf(z0,z1),fminf(z2,z3)) - 1e-4f;
    CUL(3, b, rank) = fmaxf(fmaxf(x0,x1),fmaxf(x2,x3)) + 1e-4f;
    CUL(4, b, rank) = fmaxf(fmaxf(y0,y1),fmaxf(y2,y3)) + 1e-4f;
    CUL(5, b, rank) = fmaxf(fmaxf(z0,z1),fmaxf(z2,z3)) + 1e-4f;

    const float HX = 7.0f/96.0f, HZ = 7.0f/96.0f;   // 8x8x8 slab half-extents
    auto plane = [&](float pax, float pay, float paz,
                     float pbx, float pby, float pbz,
                     float pcx, float pcy, float pcz,
                     float pox, float poy, float poz, int base) {
        float e1x = pbx-pax, e1y = pby-pay, e1z = pbz-paz;
        float e2x = pcx-pax, e2y = pcy-pay, e2z = pcz-paz;
        float nx = e1y*e2z - e1z*e2y;
        float ny = e1z*e2x - e1x*e2z;
        float nz = e1x*e2y - e1y*e2x;
        float sdot = nx*(pox-pax) + ny*(poy-pay) + nz*(poz-paz);
        if (sdot > 0.0f) { nx=-nx; ny=-ny; nz=-nz; sdot=-sdot; }
        float dpl = nx*pax + ny*pay + nz*paz;
        float n1s = fabsf(nx)+fabsf(ny)+fabsf(nz);
        float M = 1e-4f*(-sdot) + 1e-4f*n1s + 1e-4f;
        float rhs = dpl + M + (fabsf(nx)*HX + fabsf(ny)*HX + fabsf(nz)*HZ);
        CUL(base+0, b, rank) = nx;
        CUL(base+1, b, rank) = ny;
        CUL(base+2, b, rank) = nz;
        CUL(base+3, b, rank) = rhs;
    };
    plane(x1,y1,z1, x2,y2,z2, x3,y3,z3, x0,y0,z0, 6);    // opposite v0
    plane(x0,y0,z0, x2,y2,z2, x3,y3,z3, x1,y1,z1, 10);   // opposite v1
    plane(x0,y0,z0, x1,y1,z1, x3,y3,z3, x2,y2,z2, 14);   // opposite v2
    plane(x0,y0,z0, x1,y1,z1, x2,y2,z2, x3,y3,z3, 18);   // opposite v3

    auto axis = [&](float c1, float c2,
                    float t0, float t1, float t2, float t3,
                    float r, int base) {
        float tmin = fminf(fminf(t0,t1), fminf(t2,t3));
        float tmax = fmaxf(fmaxf(t0,t1), fmaxf(t2,t3));
        float M = 1e-4f*(fabsf(c1)+fabsf(c2)) + 1e-5f;
        CUL(base+0, b, rank) = c1;
        CUL(base+1, b, rank) = c2;
        CUL(base+2, b, rank) = tmin - r - M;
        CUL(base+3, b, rank) = tmax + r + M;
    };
    auto edge = [&](float xA, float yA, float zA,
                    float xB, float yB, float zB, int base) {
        float ex = xB-xA, ey = yB-yA, ez = zB-zA;
        axis(ez, -ey,
             ez*y0 - ey*z0, ez*y1 - ey*z1, ez*y2 - ey*z2, ez*y3 - ey*z3,
             fabsf(ez)*HX + fabsf(ey)*HZ, base+0);
        axis(-ez, ex,
             ex*z0 - ez*x0, ex*z1 - ez*x1, ex*z2 - ez*x2, ex*z3 - ez*x3,
             fabsf(ez)*HX + fabsf(ex)*HZ, base+4);
        axis(ey, -ex,
             ey*x0 - ex*y0, ey*x1 - ex*y1, ey*x2 - ex*y2, ey*x3 - ex*y3,
             fabsf(ey)*HX + fabsf(ex)*HX, base+8);
    };
    edge(x0,y0,z0, x1,y1,z1, 22 + 0*12);
    edge(x0,y0,z0, x2,y2,z2, 22 + 1*12);
    edge(x0,y0,z0, x3,y3,z3, 22 + 2*12);
    edge(x1,y1,z1, x2,y2,z2, 22 + 3*12);
    edge(x1,y1,z1, x3,y3,z3, 22 + 4*12);
    edge(x2,y2,z2, x3,y3,z3, 22 + 5*12);

    float* bo = body + ((size_t)b * NFAC + rank) * RECF;
    bo[0]  = det; bo[1]  = x3;  bo[2]  = y3;  bo[3]  = z3;
    bo[4]  = A00; bo[5]  = A01; bo[6]  = A02; bo[7]  = A10;
    bo[8]  = A11; bo[9]  = A12; bo[10] = A20; bo[11] = A21;
    bo[12] = A22;
    bo[13] = det * (1.0f - 1e-5f) - 1e-25f;   // dhi
    bo[14] = det * (1.0f + 1e-5f) + 1e-25f;   // mhi
    bo[15] = 0.0f;
}

// ---------------------------------------------------------------------------
// Kernel 2: 25-axis SAT mask via Z-INTERVAL reduction over 12 fat slabs per
// column. Constraints linear in slab index t (step 16/96): intersect 18
// conservative t-intervals once per (facet,column); z-loop = 2 int compares.
// Inflation +-1e-3 in t units (150x the division error); |es|<1e-7 handled
// divisionless with slack 3e-6 >= |es|*12. Conservative-superset preserved.
// ---------------------------------------------------------------------------
__global__ __launch_bounds__(512) void mask_kernel(
    const float* __restrict__ cul,
    unsigned long long* __restrict__ masks)
{
    const int col = blockIdx.x;           // 0..143 = sx*12+sy
    const int b   = blockIdx.y;
    const int f   = threadIdx.x;          // facet (sorted order)
    const int w   = threadIdx.x >> 6;

    const int sx = col / 12, sy = col % 12;
    const float cx = (float)(16*sx + 8 - VWD) / 96.0f;
    const float cy = (float)(16*sy + 8 - VWD) / 96.0f;

    float bminx=CUL(0,b,f), bminy=CUL(1,b,f), bminz=CUL(2,b,f);
    float bmaxx=CUL(3,b,f), bmaxy=CUL(4,b,f), bmaxz=CUL(5,b,f);

    const float colminx = (float)(16*sx + 1  - VWD) / 96.0f;
    const float colmaxx = (float)(16*sx + 15 - VWD) / 96.0f;
    const float colminy = (float)(16*sy + 1  - VWD) / 96.0f;
    const float colmaxy = (float)(16*sy + 15 - VWD) / 96.0f;
    bool ovxy = (bminx <= colmaxx) & (bmaxx >= colminx) &
                (bminy <= colmaxy) & (bmaxy >= colminy);

    // 6 z-invariant SAT axes (e x zhat): column-level test
#pragma unroll
    for (int e = 0; e < 6; ++e) {
        float c1 = CUL(22 + e*12 + 8,  b, f);
        float c2 = CUL(22 + e*12 + 9,  b, f);
        float lo = CUL(22 + e*12 + 10, b, f);
        float hi = CUL(22 + e*12 + 11, b, f);
        float dd = c1*cx + c2*cy;
        ovxy = ovxy & (dd >= lo) & (dd <= hi);
    }

    const float cz0   = (float)(8 - VWD) / 96.0f;   // z-center of fat slab t=0
    const float stepc = 16.0f / 96.0f;
    float tlo = -1.0f, thi = 12.0f;

    // constraint dd + es*t in [lo,hi] -> conservative t-interval, branchless
    auto addc = [&](float dd, float es, float lo, float hi) {
        bool  tiny  = fabsf(es) < 1e-7f;
        float esafe = tiny ? 1.0f : es;
        float r  = 1.0f / esafe;
        float av = (lo - dd) * r;
        float bv = (hi - dd) * r;
        float t0 = fminf(av, bv) - 1e-3f;
        float t1 = fmaxf(av, bv) + 1e-3f;
        bool ok_tiny = (dd >= lo - 3e-6f) & (dd <= hi + 3e-6f);
        t0 = tiny ? (ok_tiny ? -1.0f : 1e9f)  : t0;
        t1 = tiny ? (ok_tiny ? 13.0f : -1e9f) : t1;
        tlo = fmaxf(tlo, t0);
        thi = fminf(thi, t1);
    };

    // 4 face planes: n.c(t) - rhs <= 0  ->  dd + es*t in [-1e30, 0]
#pragma unroll
    for (int p = 0; p < 4; ++p) {
        float nx = CUL(6+p*4+0, b, f);
        float ny = CUL(6+p*4+1, b, f);
        float nz = CUL(6+p*4+2, b, f);
        float rh = CUL(6+p*4+3, b, f);
        float dd = nx*cx + ny*cy + nz*cz0 - rh;
        addc(dd, nz*stepc, -1e30f, 0.0f);
    }

    // 12 z-varying SAT axes (X-type uses cy, Y-type uses cx)
#pragma unroll
    for (int e = 0; e < 6; ++e) {
#pragma unroll
        for (int t = 0; t < 2; ++t) {
            int base = 22 + e*12 + t*4;
            float c1 = CUL(base+0, b, f);
            float c2 = CUL(base+1, b, f);
            float lo = CUL(base+2, b, f);
            float hi = CUL(base+3, b, f);
            float dd = c1 * (t == 0 ? cy : cx) + c2 * cz0;
            addc(dd, c2*stepc, lo, hi);
        }
    }

    // bbox-z as t-interval (step 16/96 -> scale 6, no division)
    const float zlo0 = (float)(1 - VWD) / 96.0f;    // fat slab t=0 voxel-z range
    const float zhi0 = (float)(15 - VWD) / 96.0f;
    tlo = fmaxf(tlo, (bminz - zhi0) * 6.0f - 1e-3f);
    thi = fminf(thi, (bmaxz - zlo0) * 6.0f + 1e-3f);

    int ilo = (int)ceilf(fmaxf(fminf(tlo, 1e8f), -1.0f));
    int ihi = (int)floorf(fminf(fmaxf(thi, -1e8f), 12.0f));

    unsigned long long* mp = masks + ((size_t)b * NSLAB + (size_t)col * 12) * 8 + w;
#pragma unroll 4
    for (int sz = 0; sz < 12; ++sz) {
        bool ov = ovxy & (sz >= ilo) & (sz <= ihi);
        unsigned long long bal = __ballot((int)ov);
        if ((threadIdx.x & 63) == 0) mp[(size_t)sz * 8] = bal;
    }
}

// ---------------------------------------------------------------------------
// Kernel 3: 2-wave blocks, one wave per 8x8x8 FAT slab (8 z-voxels/lane).
// Halves per-volume candidate chains (the latency term) and amortizes the
// per-candidate setup over 8 voxels. Per-voxel math bit-identical to ref:
// p_i = fl(fl(A_i0*dx)+fl(A_i1*dy)) cached, n_i^k = fl(p_i + fl(A_i2*dz_k));
// exact l_i>=0 sign test; det-relative shell on the sum; single __any branch
// guards the rare exact-division path.
// ---------------------------------------------------------------------------
__global__ __launch_bounds__(128) void voxelize_kernel(
    const float*              __restrict__ body,
    const unsigned long long* __restrict__ masks,
    float*                    __restrict__ out)
{
    const int b    = blockIdx.y;
    const int wave = threadIdx.x >> 6;
    const int lane = threadIdx.x & 63;
    const int slab = blockIdx.x * 2 + wave;          // 0 .. 1727
    const int sz = slab % 12;
    const int sy = (slab / 12) % 12;
    const int sx = slab / 144;
    const int ix  = sx*8 + (lane >> 3);
    const int iy  = sy*8 + (lane & 7);
    const int iz0 = sz*8;

    const float px = (float)(2*ix + 1 - VWD) / 96.0f;
    const float py = (float)(2*iy + 1 - VWD) / 96.0f;
    float pz[8];
#pragma unroll
    for (int k = 0; k < 8; ++k)
        pz[k] = (float)(2*(iz0+k) + 1 - VWD) / 96.0f;   // wave-uniform, exact

    const unsigned long long* mp = masks + ((size_t)b * NSLAB + slab) * 8;
    const float* bb = body + (size_t)b * NFAC * RECF;

    unsigned fnd = 0u;   // bit k = voxel (ix,iy,iz0+k) found
    for (int w = 0; w < 8; ++w) {
        unsigned long long m = mp[w];   // wave-uniform -> SGPR
        while (m) {
            int bit = __builtin_ctzll(m);
            m &= m - 1;
            int f = __builtin_amdgcn_readfirstlane(w * 64 + bit);
            const float* bo = bb + f * RECF;
            float det = bo[0], v3x = bo[1], v3y = bo[2], v3z = bo[3];
            float A00 = bo[4],  A01 = bo[5],  A02 = bo[6],  A10 = bo[7];
            float A11 = bo[8],  A12 = bo[9],  A20 = bo[10], A21 = bo[11];
            float A22 = bo[12], dhi = bo[13], mhi = bo[14];
            float dx = px - v3x, dy = py - v3y;
            // ref-exact partials (left-assoc, contract off)
            float p0 = A00*dx + A01*dy;
            float p1 = A10*dx + A11*dy;
            float p2 = A20*dx + A21*dy;
            float dz[8];
#pragma unroll
            for (int k = 0; k < 8; ++k) dz[k] = pz[k] - v3z;
            unsigned need = 0u;   // bit k: lane in shell, must run exact path
#pragma unroll
            for (int k = 0; k < 8; ++k) {
                // n_i bit-identical to reference's numerators
                float n0 = p0 + A02*dz[k];
                float n1 = p1 + A12*dz[k];
                float n2 = p2 + A22*dz[k];
                float sm = (n0 + n1) + n2;
                float mn = fminf(fminf(n0, n1), n2);   // v_min3_f32
                bool ge0 = (mn >= 0.0f);               // EXACT l_i>=0 test
                bool def = ge0 & (sm <= dhi);
                bool may = ge0 & (sm <= mhi);
                if (may & !def & !((fnd >> k) & 1u)) need |= (1u << k);
                if (def) fnd |= (1u << k);
            }
            if (__any(need != 0u)) {
                // exact path (rare): ref's divisions + final test, per k
#pragma unroll
                for (int k = 0; k < 8; ++k) {
                    float n0 = p0 + A02*dz[k];
                    float n1 = p1 + A12*dz[k];
                    float n2 = p2 + A22*dz[k];
                    float l0 = n0 / det;
                    float l1 = n1 / det;
                    float l2 = n2 / det;
                    float l3 = 1.0f - ((l0 + l1) + l2);
                    bool inside = (l0 >= 0.0f) & (l0 <= 1.0f) &
                                  (l1 >= 0.0f) & (l1 <= 1.0f) &
                                  (l2 >= 0.0f) & (l2 <= 1.0f) &
                                  (l3 >= 0.0f) & (l3 <= 1.0f);
                    if (((need >> k) & 1u) & inside) fnd |= (1u << k);
                }
            }
            if (__all(fnd == 255u)) goto done;
        }
    }
done:
    {
        float* op = &out[(size_t)b*(VWD*VWD*VWD) + (size_t)ix*(VWD*VWD) + iy*VWD + iz0];
        float4 v0, v1;
        v0.x = (fnd &   1u) ? 1.0f : 0.0f;
        v0.y = (fnd &   2u) ? 1.0f : 0.0f;
        v0.z = (fnd &   4u) ? 1.0f : 0.0f;
        v0.w = (fnd &   8u) ? 1.0f : 0.0f;
        v1.x = (fnd &  16u) ? 1.0f : 0.0f;
        v1.y = (fnd &  32u) ? 1.0f : 0.0f;
        v1.z = (fnd &  64u) ? 1.0f : 0.0f;
        v1.w = (fnd & 128u) ? 1.0f : 0.0f;
        *(float4*)(op + 0) = v0;
        *(float4*)(op + 4) = v1;
    }
}

extern "C" void kernel_launch(void* const* d_in, const int* in_sizes, int n_in,
                              void* d_out, int out_size, void* d_ws, size_t ws_size,
                              hipStream_t stream) {
    const float* vertices = (const float*)d_in[0];   // (8, 2048, 3) f32
    const int*   facets   = (const int*)d_in[1];     // (8, 512, 4) int
    float*       out      = (float*)d_out;           // (8, 96, 96, 96) f32

    // d_ws layout: cul SoA (1.47 MB) | body (256 KB) | masks (864 KB)
    float* cul  = (float*)d_ws;
    float* body = (float*)((char*)d_ws + (size_t)CULC * NBATCH * NFAC * 4);
    unsigned long long* msk =
        (unsigned long long*)((char*)d_ws +
                              (size_t)(CULC + RECF) * NBATCH * NFAC * 4);

    precompute_kernel<<<NBATCH, 512, 0, stream>>>(vertices, facets, cul, body);
    mask_kernel<<<dim3(144, NBATCH), 512, 0, stream>>>(cul, msk);
    dim3 grid(NSLAB / 2, NBATCH);   // 864 blocks x 2 waves = 1728 slabs/batch
    voxelize_kernel<<<grid, 128, 0, stream>>>(body, msk, out);
}

// Round 18
// 150.580 us; speedup vs baseline: 1.1289x; 1.1289x over previous
//
#include <hip/hip_runtime.h>

// Match numpy f32 semantics: no FMA contraction anywhere in this TU.
#pragma clang fp contract(off)

#define VWD 96
#define NVERT 2048
#define NFAC 512
#define NBATCH 8
#define NSLAB 3456          // 12 x 12 x 24 slabs of 8x8x4 voxels
#define RECF 16             // floats per facet body record
#define CULC 82             // cull comps (SoA): see layout below

// SoA cull addressing: component c, batch b, facet f
#define CUL(c, b, f) cul[(size_t)(c) * (NBATCH * NFAC) + (size_t)(b) * NFAC + (f)]
// layout: 0..5 bbox (minx,miny,minz,maxx,maxy,maxz)
//         6..29  6 z-invariant axes (c1,c2,lo,hi)
//         30..45 4 face planes, division-free form (P,Q,CLO,CHI)
//         46..63 6 X-type varying axes (K,LMINs,LMAXs), u = cy
//         64..81 6 Y-type varying axes (K,LMINs,LMAXs), u = cx

// ---------------------------------------------------------------------------
// Kernel 1: per-batch facet precompute, |det|-descending one-barrier rank
// sort, sign-folded body records, full 25-axis SAT cull data with ALL
// divisions hoisted here (t-interval coefficients precomputed per facet).
// Conservative: es clamped at +-1e-7 (true overlaps then have |t-bounds|
// >= ~90, outside [-1,24] -> never culls a true overlap, from the >=1e-5
// absolute margins in lo/hi/rhs); rounding slack SL folded into bounds.
// ---------------------------------------------------------------------------
__global__ __launch_bounds__(512) void precompute_kernel(
    const float* __restrict__ vertices,
    const int*   __restrict__ facets,
    float*       __restrict__ cul,
    float*       __restrict__ body)
{
    __shared__ unsigned skey[NFAC];
    const int b = blockIdx.x;
    const int j = threadIdx.x;          // one facet per thread
    const float* vb = vertices + (size_t)b * NVERT * 3;

    int4 fi = ((const int4*)facets)[b * NFAC + j];
    float x0 = vb[3*fi.x+0], y0 = vb[3*fi.x+1], z0 = vb[3*fi.x+2];
    float x1 = vb[3*fi.y+0], y1 = vb[3*fi.y+1], z1 = vb[3*fi.y+2];
    float x2 = vb[3*fi.z+0], y2 = vb[3*fi.z+1], z2 = vb[3*fi.z+2];
    float x3 = vb[3*fi.w+0], y3 = vb[3*fi.w+1], z3 = vb[3*fi.w+2];
    float a  = x0-x3, bb = x1-x3, c  = x2-x3;
    float d  = y0-y3, e  = y1-y3, f  = y2-y3;
    float g  = z0-z3, h  = z1-z3, ii = z2-z3;
    float A00 = e*ii - f*h,  A01 = c*h  - bb*ii, A02 = bb*f - c*e;
    float A10 = f*g  - d*ii, A11 = a*ii - c*g,   A12 = c*d  - a*f;
    float A20 = d*h  - e*g,  A21 = bb*g - a*h,   A22 = a*e  - bb*d;
    float det = a*(e*ii - f*h) - bb*(d*ii - f*g) + c*(d*h - e*g);
    if (det < 0.0f) {   // sign-fold (exact)
        det = -det;
        A00 = -A00; A01 = -A01; A02 = -A02;
        A10 = -A10; A11 = -A11; A12 = -A12;
        A20 = -A20; A21 = -A21; A22 = -A22;
    }
    unsigned myk = ~__float_as_uint(det);   // ascending key == descending |det|
    skey[j] = myk;
    __syncthreads();

    // rank = #{k : key_k < myk or (key_k == myk and k < j)}  -> unique slot
    int rank = 0;
    const uint4* sk4 = (const uint4*)skey;
    for (int k0 = 0; k0 < NFAC; k0 += 4) {
        uint4 kk = sk4[k0 >> 2];
        rank += (kk.x < myk) + ((kk.x == myk) & (k0 + 0 < j));
        rank += (kk.y < myk) + ((kk.y == myk) & (k0 + 1 < j));
        rank += (kk.z < myk) + ((kk.z == myk) & (k0 + 2 < j));
        rank += (kk.w < myk) + ((kk.w == myk) & (k0 + 3 < j));
    }

    CUL(0, b, rank) = fminf(fminf(x0,x1),fminf(x2,x3)) - 1e-4f;
    CUL(1, b, rank) = fminf(fminf(y0,y1),fminf(y2,y3)) - 1e-4f;
    CUL(2, b, rank) = fminf(fminf(z0,z1),fminf(z2,z3)) - 1e-4f;
    CUL(3, b, rank) = fmaxf(fmaxf(x0,x1),fmaxf(x2,x3)) + 1e-4f;
    CUL(4, b, rank) = fmaxf(fmaxf(y0,y1),fmaxf(y2,y3)) + 1e-4f;
    CUL(5, b, rank) = fmaxf(fmaxf(z0,z1),fmaxf(z2,z3)) + 1e-4f;

    const float HX = 7.0f/96.0f, HZ = 3.0f/96.0f;   // thin 8x8x4 half-extents
    const float cz0   = (float)(4 - VWD) / 96.0f;   // z-center of slab t=0
    const float stepc = 8.0f / 96.0f;

    auto safediv = [](float num, float es) {
        float esafe = (es >= 0.0f) ? fmaxf(es, 1e-7f) : fminf(es, -1e-7f);
        return num / esafe;
    };

    // 4 face planes -> division-free t-bound form (P,Q,CLO,CHI)
    auto plane = [&](float pax, float pay, float paz,
                     float pbx, float pby, float pbz,
                     float pcx, float pcy, float pcz,
                     float pox, float poy, float poz, int base) {
        float e1x = pbx-pax, e1y = pby-pay, e1z = pbz-paz;
        float e2x = pcx-pax, e2y = pcy-pay, e2z = pcz-paz;
        float nx = e1y*e2z - e1z*e2y;
        float ny = e1z*e2x - e1x*e2z;
        float nz = e1x*e2y - e1y*e2x;
        float sdot = nx*(pox-pax) + ny*(poy-pay) + nz*(poz-paz);
        if (sdot > 0.0f) { nx=-nx; ny=-ny; nz=-nz; sdot=-sdot; }
        float dpl = nx*pax + ny*pay + nz*paz;
        float n1s = fabsf(nx)+fabsf(ny)+fabsf(nz);
        float M = 1e-4f*(-sdot) + 1e-4f*n1s + 1e-4f;
        float rhs = dpl + M + (fabsf(nx)*HX + fabsf(ny)*HX + fabsf(nz)*HZ);
        // t-bound: T = C - P*cx - Q*cy ; es>0 => upper, es<0 => lower
        float es = nz * stepc;
        float P  = safediv(nx, es);
        float Q  = safediv(ny, es);
        float C  = safediv(rhs - nz*cz0, es);
        float SL = 1e-2f + 1e-6f*(fabsf(C)+fabsf(P)+fabsf(Q));
        bool pos = (es >= 0.0f);
        CUL(base+0, b, rank) = P;
        CUL(base+1, b, rank) = Q;
        CUL(base+2, b, rank) = pos ? -1e30f : (C - SL);   // CLO
        CUL(base+3, b, rank) = pos ? (C + SL) : 1e30f;    // CHI
    };
    plane(x1,y1,z1, x2,y2,z2, x3,y3,z3, x0,y0,z0, 30);   // opposite v0
    plane(x0,y0,z0, x2,y2,z2, x3,y3,z3, x1,y1,z1, 34);   // opposite v1
    plane(x0,y0,z0, x1,y1,z1, x3,y3,z3, x2,y2,z2, 38);   // opposite v2
    plane(x0,y0,z0, x1,y1,z1, x2,y2,z2, x3,y3,z3, 42);   // opposite v3

    // z-invariant axis (e x zhat): store raw (c1,c2,lo,hi)
    auto zaxis = [&](float c1, float c2,
                     float t0, float t1, float t2, float t3,
                     float r, int base) {
        float tmin = fminf(fminf(t0,t1), fminf(t2,t3));
        float tmax = fmaxf(fmaxf(t0,t1), fmaxf(t2,t3));
        float M = 1e-4f*(fabsf(c1)+fabsf(c2)) + 1e-5f;
        CUL(base+0, b, rank) = c1;
        CUL(base+1, b, rank) = c2;
        CUL(base+2, b, rank) = tmin - r - M;
        CUL(base+3, b, rank) = tmax + r + M;
    };
    // z-varying axis -> division-free (K, LMINs, LMAXs)
    auto vaxis = [&](float c1, float c2,
                     float t0, float t1, float t2, float t3,
                     float r, int base) {
        float tmin = fminf(fminf(t0,t1), fminf(t2,t3));
        float tmax = fmaxf(fmaxf(t0,t1), fmaxf(t2,t3));
        float M  = 1e-4f*(fabsf(c1)+fabsf(c2)) + 1e-5f;
        float lo = tmin - r - M;
        float hi = tmax + r + M;
        float es = c2 * stepc;
        float K  = safediv(c1, es);
        float L1 = safediv(lo - c2*cz0, es);
        float L2 = safediv(hi - c2*cz0, es);
        float SL = 1e-2f + 1e-6f*(fabsf(L1)+fabsf(L2)+fabsf(K));
        CUL(base+0, b, rank) = K;
        CUL(base+1, b, rank) = fminf(L1, L2) - SL;
        CUL(base+2, b, rank) = fmaxf(L1, L2) + SL;
    };
    auto edge = [&](float xA, float yA, float zA,
                    float xB, float yB, float zB, int ei) {
        float ex = xB-xA, ey = yB-yA, ez = zB-zA;
        // X-type (e x xhat): p(v) = ez*vy - ey*vz ; dd = ez*cy + (-ey)*cz
        vaxis(ez, -ey,
              ez*y0 - ey*z0, ez*y1 - ey*z1, ez*y2 - ey*z2, ez*y3 - ey*z3,
              fabsf(ez)*HX + fabsf(ey)*HZ, 46 + ei*3);
        // Y-type (e x yhat): p(v) = ex*vz - ez*vx ; dd = (-ez)*cx + ex*cz
        vaxis(-ez, ex,
              ex*z0 - ez*x0, ex*z1 - ez*x1, ex*z2 - ez*x2, ex*z3 - ez*x3,
              fabsf(ez)*HX + fabsf(ex)*HZ, 64 + ei*3);
        // Z-type (e x zhat): p(v) = ey*vx - ex*vy ; dd = ey*cx + (-ex)*cy
        zaxis(ey, -ex,
              ey*x0 - ex*y0, ey*x1 - ex*y1, ey*x2 - ex*y2, ey*x3 - ex*y3,
              fabsf(ey)*HX + fabsf(ex)*HX, 6 + ei*4);
    };
    edge(x0,y0,z0, x1,y1,z1, 0);
    edge(x0,y0,z0, x2,y2,z2, 1);
    edge(x0,y0,z0, x3,y3,z3, 2);
    edge(x1,y1,z1, x2,y2,z2, 3);
    edge(x1,y1,z1, x3,y3,z3, 4);
    edge(x2,y2,z2, x3,y3,z3, 5);

    float* bo = body + ((size_t)b * NFAC + rank) * RECF;
    bo[0]  = det; bo[1]  = x3;  bo[2]  = y3;  bo[3]  = z3;
    bo[4]  = A00; bo[5]  = A01; bo[6]  = A02; bo[7]  = A10;
    bo[8]  = A11; bo[9]  = A12; bo[10] = A20; bo[11] = A21;
    bo[12] = A22;
    bo[13] = det * (1.0f - 1e-5f) - 1e-25f;   // dhi
    bo[14] = det * (1.0f + 1e-5f) + 1e-25f;   // mhi
    bo[15] = 0.0f;
}

// ---------------------------------------------------------------------------
// Kernel 2: 25-axis SAT mask via DIVISION-FREE z-interval reduction. Per
// (facet,column): bbox-xy + 6 z-invariant axes -> ovxy; 4 planes + 12
// varying axes + bbox-z intersect into [tlo,thi] with precomputed t-bound
// coefficients (mul+sub+minmax each); z-loop = 2 int compares per slab.
// ---------------------------------------------------------------------------
__global__ __launch_bounds__(512) void mask_kernel(
    const float* __restrict__ cul,
    unsigned long long* __restrict__ masks)
{
    const int col = blockIdx.x;           // 0..143 = sx*12+sy
    const int b   = blockIdx.y;
    const int f   = threadIdx.x;          // facet (sorted order)
    const int w   = threadIdx.x >> 6;

    const int sx = col / 12, sy = col % 12;
    const float cx = (float)(16*sx + 8 - VWD) / 96.0f;
    const float cy = (float)(16*sy + 8 - VWD) / 96.0f;

    float bminx=CUL(0,b,f), bminy=CUL(1,b,f), bminz=CUL(2,b,f);
    float bmaxx=CUL(3,b,f), bmaxy=CUL(4,b,f), bmaxz=CUL(5,b,f);

    const float colminx = (float)(16*sx + 1  - VWD) / 96.0f;
    const float colmaxx = (float)(16*sx + 15 - VWD) / 96.0f;
    const float colminy = (float)(16*sy + 1  - VWD) / 96.0f;
    const float colmaxy = (float)(16*sy + 15 - VWD) / 96.0f;
    bool ovxy = (bminx <= colmaxx) & (bmaxx >= colminx) &
                (bminy <= colmaxy) & (bmaxy >= colminy);

    // 6 z-invariant SAT axes (e x zhat): column-level test
#pragma unroll
    for (int e = 0; e < 6; ++e) {
        float c1 = CUL(6 + e*4 + 0, b, f);
        float c2 = CUL(6 + e*4 + 1, b, f);
        float lo = CUL(6 + e*4 + 2, b, f);
        float hi = CUL(6 + e*4 + 3, b, f);
        float dd = c1*cx + c2*cy;
        ovxy = ovxy & (dd >= lo) & (dd <= hi);
    }

    float tlo = -1.0f, thi = 24.0f;

    // 4 face planes: T = C - P*cx - Q*cy, pre-sorted into [CLO,CHI]
#pragma unroll
    for (int p = 0; p < 4; ++p) {
        float P   = CUL(30+p*4+0, b, f);
        float Q   = CUL(30+p*4+1, b, f);
        float CLO = CUL(30+p*4+2, b, f);
        float CHI = CUL(30+p*4+3, b, f);
        float T2  = P*cx + Q*cy;
        tlo = fmaxf(tlo, CLO - T2);
        thi = fminf(thi, CHI - T2);
    }

    // 6 X-type varying axes (u = cy) + 6 Y-type (u = cx)
#pragma unroll
    for (int e = 0; e < 6; ++e) {
        float K  = CUL(46+e*3+0, b, f);
        float L0 = CUL(46+e*3+1, b, f);
        float L1 = CUL(46+e*3+2, b, f);
        float wv = K * cy;
        tlo = fmaxf(tlo, L0 - wv);
        thi = fminf(thi, L1 - wv);
    }
#pragma unroll
    for (int e = 0; e < 6; ++e) {
        float K  = CUL(64+e*3+0, b, f);
        float L0 = CUL(64+e*3+1, b, f);
        float L1 = CUL(64+e*3+2, b, f);
        float wv = K * cx;
        tlo = fmaxf(tlo, L0 - wv);
        thi = fminf(thi, L1 - wv);
    }

    // bbox-z as t-interval (step 8/96 -> scale 12, no division)
    const float zlo0 = (float)(1 - VWD) / 96.0f;   // slab t=0 voxel-z range
    const float zhi0 = (float)(7 - VWD) / 96.0f;
    tlo = fmaxf(tlo, (bminz - zhi0) * 12.0f - 1e-3f);
    thi = fminf(thi, (bmaxz - zlo0) * 12.0f + 1e-3f);

    int ilo = (int)ceilf(fmaxf(fminf(tlo, 1e8f), -1.0f));
    int ihi = (int)floorf(fminf(fmaxf(thi, -1e8f), 24.0f));

    unsigned long long* mp = masks + ((size_t)b * NSLAB + (size_t)col * 24) * 8 + w;
#pragma unroll 4
    for (int sz = 0; sz < 24; ++sz) {
        bool ov = ovxy & (sz >= ilo) & (sz <= ihi);
        unsigned long long bal = __ballot((int)ov);
        if ((threadIdx.x & 63) == 0) mp[(size_t)sz * 8] = bal;
    }
}

// ---------------------------------------------------------------------------
// Kernel 3 (UNCHANGED from R16 — measured 55 us): 2-wave blocks, one wave
// per 8x8x4 slab (4 z-voxels/lane). Numerators bit-identical to ref; exact
// l_i>=0 sign test; det-relative shell on the sum; single __any branch
// guards the rare exact-division path.
// ---------------------------------------------------------------------------
__global__ __launch_bounds__(128) void voxelize_kernel(
    const float*              __restrict__ body,
    const unsigned long long* __restrict__ masks,
    float*                    __restrict__ out)
{
    const int b    = blockIdx.y;
    const int wave = threadIdx.x >> 6;
    const int lane = threadIdx.x & 63;
    const int slab = blockIdx.x * 2 + wave;          // 0 .. 3455
    const int sz = slab % 24;
    const int sy = (slab / 24) % 12;
    const int sx = slab / 288;
    const int ix  = sx*8 + (lane >> 3);
    const int iy  = sy*8 + (lane & 7);
    const int iz0 = sz*4;

    const float px  = (float)(2*ix + 1 - VWD) / 96.0f;
    const float py  = (float)(2*iy + 1 - VWD) / 96.0f;
    const float pz0 = (float)(2*(iz0+0) + 1 - VWD) / 96.0f;
    const float pz1 = (float)(2*(iz0+1) + 1 - VWD) / 96.0f;
    const float pz2 = (float)(2*(iz0+2) + 1 - VWD) / 96.0f;
    const float pz3 = (float)(2*(iz0+3) + 1 - VWD) / 96.0f;

    const unsigned long long* mp = masks + ((size_t)b * NSLAB + slab) * 8;
    const float* bb = body + (size_t)b * NFAC * RECF;

    unsigned fnd = 0u;   // bit k = voxel (ix,iy,iz0+k) found
    for (int w = 0; w < 8; ++w) {
        unsigned long long m = mp[w];   // wave-uniform -> SGPR
        while (m) {
            int bit = __builtin_ctzll(m);
            m &= m - 1;
            int f = __builtin_amdgcn_readfirstlane(w * 64 + bit);
            const float* bo = bb + f * RECF;
            float det = bo[0], v3x = bo[1], v3y = bo[2], v3z = bo[3];
            float A00 = bo[4],  A01 = bo[5],  A02 = bo[6],  A10 = bo[7];
            float A11 = bo[8],  A12 = bo[9],  A20 = bo[10], A21 = bo[11];
            float A22 = bo[12], dhi = bo[13], mhi = bo[14];
            float dx = px - v3x, dy = py - v3y;
            // ref-exact partials (left-assoc, contract off)
            float p0 = A00*dx + A01*dy;
            float p1 = A10*dx + A11*dy;
            float p2 = A20*dx + A21*dy;
            float dzk0 = pz0 - v3z, dzk1 = pz1 - v3z;
            float dzk2 = pz2 - v3z, dzk3 = pz3 - v3z;
            unsigned need = 0u;   // bit k: lane in shell, must run exact path
#pragma unroll
            for (int k = 0; k < 4; ++k) {
                float dzk = (k == 0) ? dzk0 : (k == 1) ? dzk1
                          : (k == 2) ? dzk2 : dzk3;
                // n_i bit-identical to reference's numerators
                float n0 = p0 + A02*dzk;
                float n1 = p1 + A12*dzk;
                float n2 = p2 + A22*dzk;
                float sm = (n0 + n1) + n2;
                float mn = fminf(fminf(n0, n1), n2);   // v_min3_f32
                bool ge0 = (mn >= 0.0f);               // EXACT l_i>=0 test
                bool def = ge0 & (sm <= dhi);
                bool may = ge0 & (sm <= mhi);
                if (may & !def & !((fnd >> k) & 1u)) need |= (1u << k);
                if (def) fnd |= (1u << k);
            }
            if (__any(need != 0u)) {
                // exact path (rare): ref's divisions + final test, per k
#pragma unroll
                for (int k = 0; k < 4; ++k) {
                    float dzk = (k == 0) ? dzk0 : (k == 1) ? dzk1
                              : (k == 2) ? dzk2 : dzk3;
                    float n0 = p0 + A02*dzk;
                    float n1 = p1 + A12*dzk;
                    float n2 = p2 + A22*dzk;
                    float l0 = n0 / det;
                    float l1 = n1 / det;
                    float l2 = n2 / det;
                    float l3 = 1.0f - ((l0 + l1) + l2);
                    bool inside = (l0 >= 0.0f) & (l0 <= 1.0f) &
                                  (l1 >= 0.0f) & (l1 <= 1.0f) &
                                  (l2 >= 0.0f) & (l2 <= 1.0f) &
                                  (l3 >= 0.0f) & (l3 <= 1.0f);
                    if (((need >> k) & 1u) & inside) fnd |= (1u << k);
                }
            }
            if (__all(fnd == 15u)) goto done;
        }
    }
done:
    float4 v;
    v.x = (fnd & 1u) ? 1.0f : 0.0f;
    v.y = (fnd & 2u) ? 1.0f : 0.0f;
    v.z = (fnd & 4u) ? 1.0f : 0.0f;
    v.w = (fnd & 8u) ? 1.0f : 0.0f;
    *(float4*)&out[(size_t)b*(VWD*VWD*VWD) + (size_t)ix*(VWD*VWD) + iy*VWD + iz0] = v;
}

extern "C" void kernel_launch(void* const* d_in, const int* in_sizes, int n_in,
                              void* d_out, int out_size, void* d_ws, size_t ws_size,
                              hipStream_t stream) {
    const float* vertices = (const float*)d_in[0];   // (8, 2048, 3) f32
    const int*   facets   = (const int*)d_in[1];     // (8, 512, 4) int
    float*       out      = (float*)d_out;           // (8, 96, 96, 96) f32

    // d_ws layout: cul SoA (1.34 MB) | body (256 KB) | masks (1.73 MB)
    float* cul  = (float*)d_ws;
    float* body = (float*)((char*)d_ws + (size_t)CULC * NBATCH * NFAC * 4);
    unsigned long long* msk =
        (unsigned long long*)((char*)d_ws +
                              (size_t)(CULC + RECF) * NBATCH * NFAC * 4);

    precompute_kernel<<<NBATCH, 512, 0, stream>>>(vertices, facets, cul, body);
    mask_kernel<<<dim3(144, NBATCH), 512, 0, stream>>>(cul, msk);
    dim3 grid(NSLAB / 2, NBATCH);   // 1728 blocks x 2 waves = 3456 slabs/batch
    voxelize_kernel<<<grid, 128, 0, stream>>>(body, msk, out);
}

// Round 19
// 147.492 us; speedup vs baseline: 1.1526x; 1.0209x over previous
//
#include <hip/hip_runtime.h>

// Match numpy f32 semantics: no FMA contraction anywhere in this TU.
#pragma clang fp contract(off)

#define VWD 96
#define NVERT 2048
#define NFAC 512
#define NBATCH 8
#define NSLAB 3456          // 12 x 12 x 24 slabs of 8x8x4 voxels
#define RECF 16             // floats per facet body record
#define CULC 82             // cull comps (SoA): see layout below
#define CPB 6               // columns per mask block (144 = 24 groups x 6)

// SoA cull addressing: component c, batch b, facet f
#define CUL(c, b, f) cul[(size_t)(c) * (NBATCH * NFAC) + (size_t)(b) * NFAC + (f)]
// layout: 0..5 bbox (minx,miny,minz,maxx,maxy,maxz)
//         6..29  6 z-invariant axes (c1,c2,lo,hi)
//         30..45 4 face planes, division-free form (P,Q,CLO,CHI)
//         46..63 6 X-type varying axes (K,LMINs,LMAXs), u = cy
//         64..81 6 Y-type varying axes (K,LMINs,LMAXs), u = cx

// ---------------------------------------------------------------------------
// Kernel 1 (unchanged from R18): per-batch facet precompute, |det|-descending
// one-barrier rank sort, sign-folded body records, full 25-axis SAT cull data
// with ALL divisions hoisted here (t-interval coefficients per facet).
// Conservative: es clamped at +-1e-7; rounding slack SL folded into bounds.
// ---------------------------------------------------------------------------
__global__ __launch_bounds__(512) void precompute_kernel(
    const float* __restrict__ vertices,
    const int*   __restrict__ facets,
    float*       __restrict__ cul,
    float*       __restrict__ body)
{
    __shared__ unsigned skey[NFAC];
    const int b = blockIdx.x;
    const int j = threadIdx.x;          // one facet per thread
    const float* vb = vertices + (size_t)b * NVERT * 3;

    int4 fi = ((const int4*)facets)[b * NFAC + j];
    float x0 = vb[3*fi.x+0], y0 = vb[3*fi.x+1], z0 = vb[3*fi.x+2];
    float x1 = vb[3*fi.y+0], y1 = vb[3*fi.y+1], z1 = vb[3*fi.y+2];
    float x2 = vb[3*fi.z+0], y2 = vb[3*fi.z+1], z2 = vb[3*fi.z+2];
    float x3 = vb[3*fi.w+0], y3 = vb[3*fi.w+1], z3 = vb[3*fi.w+2];
    float a  = x0-x3, bb = x1-x3, c  = x2-x3;
    float d  = y0-y3, e  = y1-y3, f  = y2-y3;
    float g  = z0-z3, h  = z1-z3, ii = z2-z3;
    float A00 = e*ii - f*h,  A01 = c*h  - bb*ii, A02 = bb*f - c*e;
    float A10 = f*g  - d*ii, A11 = a*ii - c*g,   A12 = c*d  - a*f;
    float A20 = d*h  - e*g,  A21 = bb*g - a*h,   A22 = a*e  - bb*d;
    float det = a*(e*ii - f*h) - bb*(d*ii - f*g) + c*(d*h - e*g);
    if (det < 0.0f) {   // sign-fold (exact)
        det = -det;
        A00 = -A00; A01 = -A01; A02 = -A02;
        A10 = -A10; A11 = -A11; A12 = -A12;
        A20 = -A20; A21 = -A21; A22 = -A22;
    }
    unsigned myk = ~__float_as_uint(det);   // ascending key == descending |det|
    skey[j] = myk;
    __syncthreads();

    int rank = 0;
    const uint4* sk4 = (const uint4*)skey;
    for (int k0 = 0; k0 < NFAC; k0 += 4) {
        uint4 kk = sk4[k0 >> 2];
        rank += (kk.x < myk) + ((kk.x == myk) & (k0 + 0 < j));
        rank += (kk.y < myk) + ((kk.y == myk) & (k0 + 1 < j));
        rank += (kk.z < myk) + ((kk.z == myk) & (k0 + 2 < j));
        rank += (kk.w < myk) + ((kk.w == myk) & (k0 + 3 < j));
    }

    CUL(0, b, rank) = fminf(fminf(x0,x1),fminf(x2,x3)) - 1e-4f;
    CUL(1, b, rank) = fminf(fminf(y0,y1),fminf(y2,y3)) - 1e-4f;
    CUL(2, b, rank) = fminf(fminf(z0,z1),fminf(z2,z3)) - 1e-4f;
    CUL(3, b, rank) = fmaxf(fmaxf(x0,x1),fmaxf(x2,x3)) + 1e-4f;
    CUL(4, b, rank) = fmaxf(fmaxf(y0,y1),fmaxf(y2,y3)) + 1e-4f;
    CUL(5, b, rank) = fmaxf(fmaxf(z0,z1),fmaxf(z2,z3)) + 1e-4f;

    const float HX = 7.0f/96.0f, HZ = 3.0f/96.0f;   // thin 8x8x4 half-extents
    const float cz0   = (float)(4 - VWD) / 96.0f;   // z-center of slab t=0
    const float stepc = 8.0f / 96.0f;

    auto safediv = [](float num, float es) {
        float esafe = (es >= 0.0f) ? fmaxf(es, 1e-7f) : fminf(es, -1e-7f);
        return num / esafe;
    };

    auto plane = [&](float pax, float pay, float paz,
                     float pbx, float pby, float pbz,
                     float pcx, float pcy, float pcz,
                     float pox, float poy, float poz, int base) {
        float e1x = pbx-pax, e1y = pby-pay, e1z = pbz-paz;
        float e2x = pcx-pax, e2y = pcy-pay, e2z = pcz-paz;
        float nx = e1y*e2z - e1z*e2y;
        float ny = e1z*e2x - e1x*e2z;
        float nz = e1x*e2y - e1y*e2x;
        float sdot = nx*(pox-pax) + ny*(poy-pay) + nz*(poz-paz);
        if (sdot > 0.0f) { nx=-nx; ny=-ny; nz=-nz; sdot=-sdot; }
        float dpl = nx*pax + ny*pay + nz*paz;
        float n1s = fabsf(nx)+fabsf(ny)+fabsf(nz);
        float M = 1e-4f*(-sdot) + 1e-4f*n1s + 1e-4f;
        float rhs = dpl + M + (fabsf(nx)*HX + fabsf(ny)*HX + fabsf(nz)*HZ);
        float es = nz * stepc;
        float P  = safediv(nx, es);
        float Q  = safediv(ny, es);
        float C  = safediv(rhs - nz*cz0, es);
        float SL = 1e-2f + 1e-6f*(fabsf(C)+fabsf(P)+fabsf(Q));
        bool pos = (es >= 0.0f);
        CUL(base+0, b, rank) = P;
        CUL(base+1, b, rank) = Q;
        CUL(base+2, b, rank) = pos ? -1e30f : (C - SL);   // CLO
        CUL(base+3, b, rank) = pos ? (C + SL) : 1e30f;    // CHI
    };
    plane(x1,y1,z1, x2,y2,z2, x3,y3,z3, x0,y0,z0, 30);   // opposite v0
    plane(x0,y0,z0, x2,y2,z2, x3,y3,z3, x1,y1,z1, 34);   // opposite v1
    plane(x0,y0,z0, x1,y1,z1, x3,y3,z3, x2,y2,z2, 38);   // opposite v2
    plane(x0,y0,z0, x1,y1,z1, x2,y2,z2, x3,y3,z3, 42);   // opposite v3

    auto zaxis = [&](float c1, float c2,
                     float t0, float t1, float t2, float t3,
                     float r, int base) {
        float tmin = fminf(fminf(t0,t1), fminf(t2,t3));
        float tmax = fmaxf(fmaxf(t0,t1), fmaxf(t2,t3));
        float M = 1e-4f*(fabsf(c1)+fabsf(c2)) + 1e-5f;
        CUL(base+0, b, rank) = c1;
        CUL(base+1, b, rank) = c2;
        CUL(base+2, b, rank) = tmin - r - M;
        CUL(base+3, b, rank) = tmax + r + M;
    };
    auto vaxis = [&](float c1, float c2,
                     float t0, float t1, float t2, float t3,
                     float r, int base) {
        float tmin = fminf(fminf(t0,t1), fminf(t2,t3));
        float tmax = fmaxf(fmaxf(t0,t1), fmaxf(t2,t3));
        float M  = 1e-4f*(fabsf(c1)+fabsf(c2)) + 1e-5f;
        float lo = tmin - r - M;
        float hi = tmax + r + M;
        float es = c2 * stepc;
        float K  = safediv(c1, es);
        float L1 = safediv(lo - c2*cz0, es);
        float L2 = safediv(hi - c2*cz0, es);
        float SL = 1e-2f + 1e-6f*(fabsf(L1)+fabsf(L2)+fabsf(K));
        CUL(base+0, b, rank) = K;
        CUL(base+1, b, rank) = fminf(L1, L2) - SL;
        CUL(base+2, b, rank) = fmaxf(L1, L2) + SL;
    };
    auto edge = [&](float xA, float yA, float zA,
                    float xB, float yB, float zB, int ei) {
        float ex = xB-xA, ey = yB-yA, ez = zB-zA;
        vaxis(ez, -ey,
              ez*y0 - ey*z0, ez*y1 - ey*z1, ez*y2 - ey*z2, ez*y3 - ey*z3,
              fabsf(ez)*HX + fabsf(ey)*HZ, 46 + ei*3);
        vaxis(-ez, ex,
              ex*z0 - ez*x0, ex*z1 - ez*x1, ex*z2 - ez*x2, ex*z3 - ez*x3,
              fabsf(ez)*HX + fabsf(ex)*HZ, 64 + ei*3);
        zaxis(ey, -ex,
              ey*x0 - ex*y0, ey*x1 - ex*y1, ey*x2 - ex*y2, ey*x3 - ex*y3,
              fabsf(ey)*HX + fabsf(ex)*HX, 6 + ei*4);
    };
    edge(x0,y0,z0, x1,y1,z1, 0);
    edge(x0,y0,z0, x2,y2,z2, 1);
    edge(x0,y0,z0, x3,y3,z3, 2);
    edge(x1,y1,z1, x2,y2,z2, 3);
    edge(x1,y1,z1, x3,y3,z3, 4);
    edge(x2,y2,z2, x3,y3,z3, 5);

    float* bo = body + ((size_t)b * NFAC + rank) * RECF;
    bo[0]  = det; bo[1]  = x3;  bo[2]  = y3;  bo[3]  = z3;
    bo[4]  = A00; bo[5]  = A01; bo[6]  = A02; bo[7]  = A10;
    bo[8]  = A11; bo[9]  = A12; bo[10] = A20; bo[11] = A21;
    bo[12] = A22;
    bo[13] = det * (1.0f - 1e-5f) - 1e-25f;   // dhi
    bo[14] = det * (1.0f + 1e-5f) + 1e-25f;   // mhi
    bo[15] = 0.0f;
}

// ---------------------------------------------------------------------------
// Kernel 2: MULTI-COLUMN division-free SAT mask. Each block handles CPB=6
// columns for one batch: every constraint's coefficients are loaded ONCE per
// thread and applied to 6 column centers (t-intervals in registers) ->
// 6x less CUL traffic (193 -> 32 MB), same per-column formulas as R18
// (identical margins -> still a conservative superset).
// ---------------------------------------------------------------------------
__global__ __launch_bounds__(512) void mask_kernel(
    const float* __restrict__ cul,
    unsigned long long* __restrict__ masks)
{
    const int grp = blockIdx.x;           // 0..23 column group
    const int b   = blockIdx.y;
    const int f   = threadIdx.x;          // facet (sorted order)
    const int w   = threadIdx.x >> 6;
    const int colbase = grp * CPB;

    float cx[CPB], cy[CPB];
    float cminx[CPB], cmaxx[CPB], cminy[CPB], cmaxy[CPB];
#pragma unroll
    for (int jj = 0; jj < CPB; ++jj) {
        int col = colbase + jj;
        int sx = col / 12, sy = col % 12;
        cx[jj]    = (float)(16*sx + 8  - VWD) / 96.0f;
        cy[jj]    = (float)(16*sy + 8  - VWD) / 96.0f;
        cminx[jj] = (float)(16*sx + 1  - VWD) / 96.0f;
        cmaxx[jj] = (float)(16*sx + 15 - VWD) / 96.0f;
        cminy[jj] = (float)(16*sy + 1  - VWD) / 96.0f;
        cmaxy[jj] = (float)(16*sy + 15 - VWD) / 96.0f;
    }

    float bminx=CUL(0,b,f), bminy=CUL(1,b,f), bminz=CUL(2,b,f);
    float bmaxx=CUL(3,b,f), bmaxy=CUL(4,b,f), bmaxz=CUL(5,b,f);

    unsigned ovbits = 0u;   // bit jj: column jj passes all xy tests
#pragma unroll
    for (int jj = 0; jj < CPB; ++jj) {
        bool ov = (bminx <= cmaxx[jj]) & (bmaxx >= cminx[jj]) &
                  (bminy <= cmaxy[jj]) & (bmaxy >= cminy[jj]);
        ovbits |= ov ? (1u << jj) : 0u;
    }

    // 6 z-invariant SAT axes (e x zhat)
#pragma unroll
    for (int e = 0; e < 6; ++e) {
        float c1 = CUL(6 + e*4 + 0, b, f);
        float c2 = CUL(6 + e*4 + 1, b, f);
        float lo = CUL(6 + e*4 + 2, b, f);
        float hi = CUL(6 + e*4 + 3, b, f);
#pragma unroll
        for (int jj = 0; jj < CPB; ++jj) {
            float dd = c1*cx[jj] + c2*cy[jj];
            bool ok = (dd >= lo) & (dd <= hi);
            ovbits &= ok ? 0xFFFFFFFFu : ~(1u << jj);
        }
    }

    float tlo[CPB], thi[CPB];
#pragma unroll
    for (int jj = 0; jj < CPB; ++jj) { tlo[jj] = -1.0f; thi[jj] = 24.0f; }

    // 4 face planes: T = C - P*cx - Q*cy, pre-sorted into [CLO,CHI]
#pragma unroll
    for (int p = 0; p < 4; ++p) {
        float P   = CUL(30+p*4+0, b, f);
        float Q   = CUL(30+p*4+1, b, f);
        float CLO = CUL(30+p*4+2, b, f);
        float CHI = CUL(30+p*4+3, b, f);
#pragma unroll
        for (int jj = 0; jj < CPB; ++jj) {
            float T2 = P*cx[jj] + Q*cy[jj];
            tlo[jj] = fmaxf(tlo[jj], CLO - T2);
            thi[jj] = fminf(thi[jj], CHI - T2);
        }
    }

    // 6 X-type varying axes (u = cy) + 6 Y-type (u = cx)
#pragma unroll
    for (int e = 0; e < 6; ++e) {
        float K  = CUL(46+e*3+0, b, f);
        float L0 = CUL(46+e*3+1, b, f);
        float L1 = CUL(46+e*3+2, b, f);
#pragma unroll
        for (int jj = 0; jj < CPB; ++jj) {
            float wv = K * cy[jj];
            tlo[jj] = fmaxf(tlo[jj], L0 - wv);
            thi[jj] = fminf(thi[jj], L1 - wv);
        }
    }
#pragma unroll
    for (int e = 0; e < 6; ++e) {
        float K  = CUL(64+e*3+0, b, f);
        float L0 = CUL(64+e*3+1, b, f);
        float L1 = CUL(64+e*3+2, b, f);
#pragma unroll
        for (int jj = 0; jj < CPB; ++jj) {
            float wv = K * cx[jj];
            tlo[jj] = fmaxf(tlo[jj], L0 - wv);
            thi[jj] = fminf(thi[jj], L1 - wv);
        }
    }

    // bbox-z t-interval: column-independent -> hoisted
    const float zlo0 = (float)(1 - VWD) / 96.0f;
    const float zhi0 = (float)(7 - VWD) / 96.0f;
    const float tzlo = (bminz - zhi0) * 12.0f - 1e-3f;
    const float tzhi = (bmaxz - zlo0) * 12.0f + 1e-3f;

#pragma unroll
    for (int jj = 0; jj < CPB; ++jj) {
        float tl = fmaxf(tlo[jj], tzlo);
        float th = fminf(thi[jj], tzhi);
        int ilo = (int)ceilf(fmaxf(fminf(tl, 1e8f), -1.0f));
        int ihi = (int)floorf(fminf(fmaxf(th, -1e8f), 24.0f));
        bool ovc = (ovbits >> jj) & 1u;
        unsigned long long* mp =
            masks + ((size_t)b * NSLAB + (size_t)(colbase + jj) * 24) * 8 + w;
#pragma unroll 4
        for (int sz = 0; sz < 24; ++sz) {
            bool ov = ovc & (sz >= ilo) & (sz <= ihi);
            unsigned long long bal = __ballot((int)ov);
            if ((threadIdx.x & 63) == 0) mp[(size_t)sz * 8] = bal;
        }
    }
}

// ---------------------------------------------------------------------------
// Kernel 3 (UNCHANGED from R18 — measured 52.5 us): 2-wave blocks, one wave
// per 8x8x4 slab (4 z-voxels/lane). Numerators bit-identical to ref; exact
// l_i>=0 sign test; det-relative shell on the sum; single __any branch
// guards the rare exact-division path.
// ---------------------------------------------------------------------------
__global__ __launch_bounds__(128) void voxelize_kernel(
    const float*              __restrict__ body,
    const unsigned long long* __restrict__ masks,
    float*                    __restrict__ out)
{
    const int b    = blockIdx.y;
    const int wave = threadIdx.x >> 6;
    const int lane = threadIdx.x & 63;
    const int slab = blockIdx.x * 2 + wave;          // 0 .. 3455
    const int sz = slab % 24;
    const int sy = (slab / 24) % 12;
    const int sx = slab / 288;
    const int ix  = sx*8 + (lane >> 3);
    const int iy  = sy*8 + (lane & 7);
    const int iz0 = sz*4;

    const float px  = (float)(2*ix + 1 - VWD) / 96.0f;
    const float py  = (float)(2*iy + 1 - VWD) / 96.0f;
    const float pz0 = (float)(2*(iz0+0) + 1 - VWD) / 96.0f;
    const float pz1 = (float)(2*(iz0+1) + 1 - VWD) / 96.0f;
    const float pz2 = (float)(2*(iz0+2) + 1 - VWD) / 96.0f;
    const float pz3 = (float)(2*(iz0+3) + 1 - VWD) / 96.0f;

    const unsigned long long* mp = masks + ((size_t)b * NSLAB + slab) * 8;
    const float* bb = body + (size_t)b * NFAC * RECF;

    unsigned fnd = 0u;   // bit k = voxel (ix,iy,iz0+k) found
    for (int w = 0; w < 8; ++w) {
        unsigned long long m = mp[w];   // wave-uniform -> SGPR
        while (m) {
            int bit = __builtin_ctzll(m);
            m &= m - 1;
            int f = __builtin_amdgcn_readfirstlane(w * 64 + bit);
            const float* bo = bb + f * RECF;
            float det = bo[0], v3x = bo[1], v3y = bo[2], v3z = bo[3];
            float A00 = bo[4],  A01 = bo[5],  A02 = bo[6],  A10 = bo[7];
            float A11 = bo[8],  A12 = bo[9],  A20 = bo[10], A21 = bo[11];
            float A22 = bo[12], dhi = bo[13], mhi = bo[14];
            float dx = px - v3x, dy = py - v3y;
            // ref-exact partials (left-assoc, contract off)
            float p0 = A00*dx + A01*dy;
            float p1 = A10*dx + A11*dy;
            float p2 = A20*dx + A21*dy;
            float dzk0 = pz0 - v3z, dzk1 = pz1 - v3z;
            float dzk2 = pz2 - v3z, dzk3 = pz3 - v3z;
            unsigned need = 0u;   // bit k: lane in shell, must run exact path
#pragma unroll
            for (int k = 0; k < 4; ++k) {
                float dzk = (k == 0) ? dzk0 : (k == 1) ? dzk1
                          : (k == 2) ? dzk2 : dzk3;
                // n_i bit-identical to reference's numerators
                float n0 = p0 + A02*dzk;
                float n1 = p1 + A12*dzk;
                float n2 = p2 + A22*dzk;
                float sm = (n0 + n1) + n2;
                float mn = fminf(fminf(n0, n1), n2);   // v_min3_f32
                bool ge0 = (mn >= 0.0f);               // EXACT l_i>=0 test
                bool def = ge0 & (sm <= dhi);
                bool may = ge0 & (sm <= mhi);
                if (may & !def & !((fnd >> k) & 1u)) need |= (1u << k);
                if (def) fnd |= (1u << k);
            }
            if (__any(need != 0u)) {
                // exact path (rare): ref's divisions + final test, per k
#pragma unroll
                for (int k = 0; k < 4; ++k) {
                    float dzk = (k == 0) ? dzk0 : (k == 1) ? dzk1
                              : (k == 2) ? dzk2 : dzk3;
                    float n0 = p0 + A02*dzk;
                    float n1 = p1 + A12*dzk;
                    float n2 = p2 + A22*dzk;
                    float l0 = n0 / det;
                    float l1 = n1 / det;
                    float l2 = n2 / det;
                    float l3 = 1.0f - ((l0 + l1) + l2);
                    bool inside = (l0 >= 0.0f) & (l0 <= 1.0f) &
                                  (l1 >= 0.0f) & (l1 <= 1.0f) &
                                  (l2 >= 0.0f) & (l2 <= 1.0f) &
                                  (l3 >= 0.0f) & (l3 <= 1.0f);
                    if (((need >> k) & 1u) & inside) fnd |= (1u << k);
                }
            }
            if (__all(fnd == 15u)) goto done;
        }
    }
done:
    float4 v;
    v.x = (fnd & 1u) ? 1.0f : 0.0f;
    v.y = (fnd & 2u) ? 1.0f : 0.0f;
    v.z = (fnd & 4u) ? 1.0f : 0.0f;
    v.w = (fnd & 8u) ? 1.0f : 0.0f;
    *(float4*)&out[(size_t)b*(VWD*VWD*VWD) + (size_t)ix*(VWD*VWD) + iy*VWD + iz0] = v;
}

extern "C" void kernel_launch(void* const* d_in, const int* in_sizes, int n_in,
                              void* d_out, int out_size, void* d_ws, size_t ws_size,
                              hipStream_t stream) {
    const float* vertices = (const float*)d_in[0];   // (8, 2048, 3) f32
    const int*   facets   = (const int*)d_in[1];     // (8, 512, 4) int
    float*       out      = (float*)d_out;           // (8, 96, 96, 96) f32

    // d_ws layout: cul SoA (1.34 MB) | body (256 KB) | masks (1.73 MB)
    float* cul  = (float*)d_ws;
    float* body = (float*)((char*)d_ws + (size_t)CULC * NBATCH * NFAC * 4);
    unsigned long long* msk =
        (unsigned long long*)((char*)d_ws +
                              (size_t)(CULC + RECF) * NBATCH * NFAC * 4);

    precompute_kernel<<<NBATCH, 512, 0, stream>>>(vertices, facets, cul, body);
    mask_kernel<<<dim3(144 / CPB, NBATCH), 512, 0, stream>>>(cul, msk);
    dim3 grid(NSLAB / 2, NBATCH);   // 1728 blocks x 2 waves = 3456 slabs/batch
    voxelize_kernel<<<grid, 128, 0, stream>>>(body, msk, out);
}